// Round 6
// baseline (57.918 us; speedup 1.0000x reference)
//
#include <hip/hip_runtime.h>
#include <hip/hip_bf16.h>
#include <stdint.h>

// PairRelationEncoder: out[b,e,s] = b2[s] + sum_r W2[s,r]*relu(b1[r] + sum_f W1[r,f]*pair[b,e,f])
// pair = [zi, zj, zi-zj, zi*zj] folded to [zi, zj, zi*zj]: Wzi=W1a+W1c, Wzj=W1b-W1c, Wpr=W1d.
// B=4 N=4096 D=64 E=131072 R=64. Out f32 (4,131072,64).
//
// R6: 32x32x16 MFMA; layer1->layer2 hand-off IN REGISTERS via cvt_pk_bf16 + permlane32_swap
// (T12). No h1 LDS buffer, no intra-loop barriers. Per 32-pair subtile: 8 gather loads,
// 32 ds_read_b128 (weights), 32 MFMA, 8 stores. Bias via LDS broadcast tables.

typedef __attribute__((ext_vector_type(8)))  __bf16 bf16x8;
typedef __attribute__((ext_vector_type(4)))  float  f32x4;
typedef __attribute__((ext_vector_type(16))) float  f32x16;
typedef __attribute__((ext_vector_type(4)))  uint32_t u32x4;

#define E_TOT 131072
#define N_TOK 4096
#define ROWS_PER_BLOCK 512
#define NSUB 2            // per wave: 2 subtiles x 32 pairs (8 waves -> 512 rows/block)
#define Z_ELEMS (4 * N_TOK * 64)

// ---- prologue: f32 z -> bf16 z in workspace ----
__global__ __launch_bounds__(256) void zcast_kernel(const float* __restrict__ z,
                                                    __bf16* __restrict__ zb)
{
    const int t = blockIdx.x * 256 + threadIdx.x;
    const float4 a = ((const float4*)z)[2 * t];
    const float4 b = ((const float4*)z)[2 * t + 1];
    bf16x8 r;
    r[0] = (__bf16)a.x; r[1] = (__bf16)a.y; r[2] = (__bf16)a.z; r[3] = (__bf16)a.w;
    r[4] = (__bf16)b.x; r[5] = (__bf16)b.y; r[6] = (__bf16)b.z; r[7] = (__bf16)b.w;
    ((bf16x8*)zb)[t] = r;
}

__device__ __forceinline__ f32x16 mfma32(bf16x8 a, bf16x8 b, f32x16 c) {
    return __builtin_amdgcn_mfma_f32_32x32x16_bf16(a, b, c, 0, 0, 0);
}

__device__ __forceinline__ bf16x8 pk8(float4 a, float4 b) {
    bf16x8 r;
    r[0] = (__bf16)a.x; r[1] = (__bf16)a.y; r[2] = (__bf16)a.z; r[3] = (__bf16)a.w;
    r[4] = (__bf16)b.x; r[5] = (__bf16)b.y; r[6] = (__bf16)b.z; r[7] = (__bf16)b.w;
    return r;
}
__device__ __forceinline__ float4 f4add(float4 a, float4 b){ return make_float4(a.x+b.x, a.y+b.y, a.z+b.z, a.w+b.w); }
__device__ __forceinline__ float4 f4sub(float4 a, float4 b){ return make_float4(a.x-b.x, a.y-b.y, a.z-b.z, a.w-b.w); }

__device__ __forceinline__ bf16x8 bmul(bf16x8 a, bf16x8 b) {
    bf16x8 r;
#pragma unroll
    for (int t = 0; t < 8; ++t)
        r[t] = (__bf16)((float)a[t] * (float)b[t]);
    return r;
}

__device__ __forceinline__ uint32_t cvtpk(float lo, float hi) {
    uint32_t w;
    asm("v_cvt_pk_bf16_f32 %0, %1, %2" : "=v"(w) : "v"(lo), "v"(hi));
    return w;
}

// relu + pack one rt's 16 accumulators into two layer-2 B-frags (kappa=2rt, 2rt+1).
// word(p,u) = [r=rt*32+8p+4hi+2u, +1]; swap(w(2c,0),w(2c+1,0)) -> frag m0,m2 (both hi).
__device__ __forceinline__ void epi(const f32x16 acc, bf16x8& fA, bf16x8& fB) {
    float v[16];
#pragma unroll
    for (int t = 0; t < 16; ++t) v[t] = fmaxf(acc[t], 0.f);
    uint32_t w00 = cvtpk(v[0],  v[1]);
    uint32_t w01 = cvtpk(v[2],  v[3]);
    uint32_t w10 = cvtpk(v[4],  v[5]);
    uint32_t w11 = cvtpk(v[6],  v[7]);
    uint32_t w20 = cvtpk(v[8],  v[9]);
    uint32_t w21 = cvtpk(v[10], v[11]);
    uint32_t w30 = cvtpk(v[12], v[13]);
    uint32_t w31 = cvtpk(v[14], v[15]);
    asm("v_permlane32_swap_b32 %0, %1" : "+v"(w00), "+v"(w10));
    asm("v_permlane32_swap_b32 %0, %1" : "+v"(w01), "+v"(w11));
    asm("v_permlane32_swap_b32 %0, %1" : "+v"(w20), "+v"(w30));
    asm("v_permlane32_swap_b32 %0, %1" : "+v"(w21), "+v"(w31));
    u32x4 a = {w00, w01, w10, w11};
    u32x4 b = {w20, w21, w30, w31};
    fA = __builtin_bit_cast(bf16x8, a);
    fB = __builtin_bit_cast(bf16x8, b);
}

__device__ __forceinline__ f32x16 bias_init(const float* tb, int base) {
    f32x16 a;
#pragma unroll
    for (int p = 0; p < 4; ++p) {
        f32x4 c = *(const f32x4*)(tb + base + 4 * p);
        a[4*p+0] = c[0]; a[4*p+1] = c[1]; a[4*p+2] = c[2]; a[4*p+3] = c[3];
    }
    return a;
}

__global__ __launch_bounds__(512, 4) void PairRelationEncoder_62775241998442_kernel(
    const __bf16* __restrict__ zw, const int* __restrict__ pairs,
    const float* __restrict__ W1, const float* __restrict__ b1,
    const float* __restrict__ W2, const float* __restrict__ b2,
    float* __restrict__ out)
{
    const int tid  = threadIdx.x;
    const int wave = tid >> 6;
    const int lane = tid & 63;
    const int el = lane & 31;   // MFMA row (A) / col (B,C)
    const int hi = lane >> 5;   // k-half

    // bijective XCD-chunked swizzle (1024 blocks, 8 XCDs)
    const int bid = (int)(blockIdx.x & 7) * 128 + ((int)blockIdx.x >> 3);
    const int m0 = bid * ROWS_PER_BLOCK;
    const int b  = m0 >> 17;
    const int e0 = m0 & (E_TOT - 1);
    const __bf16* zb = zw + ((size_t)b * N_TOK * 64);

    // hoisted pairs
    int2 ijv[NSUB];
#pragma unroll
    for (int st = 0; st < NSUB; ++st)
        ijv[st] = *(const int2*)(pairs + 2 * (size_t)(e0 + (st * 8 + wave) * 32 + el));

    // LDS: W1f bf16 [r(64)][k(192)] swz + W2 bf16 [s(64)][r(64)] swz + bias tables.
    // 24576 + 8192 + 256 + 256 = 33280 B.
    __shared__ __bf16 w1s[64 * 192];
    __shared__ __bf16 w2s[64 * 64];
    __shared__ float  tb1[64];
    __shared__ float  tb2[64];

    // ---- one-time weight staging (same as R5): 4 parts x 128 threads ----
    {
        const int part = tid >> 7;            // 0:zi 1:zj 2:pr 3:W2
        const int scol = tid & 63;
        const int c8b  = ((tid >> 6) & 1) * 4;
        const int cswz = (scol & 7) << 4;
        if (part < 3) {
            const float* wr = W1 + (size_t)scol * 256;
            char* dst = (char*)w1s + scol * 384;
#pragma unroll
            for (int c = 0; c < 4; ++c) {
                const int c8 = c8b + c;
                float4 p0, p1;
                if (part == 0) {
                    float4 a0 = *(const float4*)(wr + c8*8);
                    float4 a1 = *(const float4*)(wr + c8*8 + 4);
                    float4 c0 = *(const float4*)(wr + 128 + c8*8);
                    float4 c1 = *(const float4*)(wr + 128 + c8*8 + 4);
                    p0 = f4add(a0, c0); p1 = f4add(a1, c1);
                } else if (part == 1) {
                    float4 a0 = *(const float4*)(wr + 64 + c8*8);
                    float4 a1 = *(const float4*)(wr + 64 + c8*8 + 4);
                    float4 c0 = *(const float4*)(wr + 128 + c8*8);
                    float4 c1 = *(const float4*)(wr + 128 + c8*8 + 4);
                    p0 = f4sub(a0, c0); p1 = f4sub(a1, c1);
                } else {
                    p0 = *(const float4*)(wr + 192 + c8*8);
                    p1 = *(const float4*)(wr + 192 + c8*8 + 4);
                }
                *(bf16x8*)(dst + ((part * 128 + c8 * 16) ^ cswz)) = pk8(p0, p1);
            }
        } else {
            const float* wr = W2 + (size_t)scol * 64;
            char* dst = (char*)w2s + scol * 128;
#pragma unroll
            for (int c = 0; c < 4; ++c) {
                const int c8 = c8b + c;
                float4 p0 = *(const float4*)(wr + c8*8);
                float4 p1 = *(const float4*)(wr + c8*8 + 4);
                *(bf16x8*)(dst + ((c8 * 16) ^ cswz)) = pk8(p0, p1);
            }
        }
        // bias tables: tb[hi*32 + rt*16 + reg] = bias[rt*32 + (reg&3) + 8*((reg>>2)&3) + 4*hi]
        if (tid < 64)
            tb1[tid] = b1[((tid >> 4) & 1) * 32 + (tid & 3) + 8 * ((tid >> 2) & 3) + 4 * (tid >> 5)];
        else if (tid < 128) {
            const int t = tid - 64;
            tb2[t] = b2[((t >> 4) & 1) * 32 + (t & 3) + 8 * ((t >> 2) & 3) + 4 * (t >> 5)];
        }
    }

    __syncthreads();

    const int sw = (el & 7) << 4;
    const char* w1b = (const char*)w1s;
    const char* w2b = (const char*)w2s;

#pragma unroll
    for (int st = 0; st < NSUB; ++st) {
        // ---- gather: 8x 16B loads are the layer-1 B-frags ----
        const __bf16* zri = zb + (size_t)ijv[st].x * 64;
        const __bf16* zrj = zb + (size_t)ijv[st].y * 64;
        bf16x8 zi0 = *(const bf16x8*)(zri +      hi * 8);
        bf16x8 zi1 = *(const bf16x8*)(zri + 16 + hi * 8);
        bf16x8 zi2 = *(const bf16x8*)(zri + 32 + hi * 8);
        bf16x8 zi3 = *(const bf16x8*)(zri + 48 + hi * 8);
        bf16x8 zj0 = *(const bf16x8*)(zrj +      hi * 8);
        bf16x8 zj1 = *(const bf16x8*)(zrj + 16 + hi * 8);
        bf16x8 zj2 = *(const bf16x8*)(zrj + 32 + hi * 8);
        bf16x8 zj3 = *(const bf16x8*)(zrj + 48 + hi * 8);

        // ---- layer 1: h1^T[r][e], 24 MFMA over K=192 ----
        f32x16 acc0 = bias_init(tb1, hi * 32);        // rt=0: r 0..31
        f32x16 acc1 = bias_init(tb1, hi * 32 + 16);   // rt=1: r 32..63

#pragma unroll
        for (int kt = 0; kt < 12; ++kt) {
            bf16x8 bf;
            if      (kt == 0) bf = zi0;
            else if (kt == 1) bf = zi1;
            else if (kt == 2) bf = zi2;
            else if (kt == 3) bf = zi3;
            else if (kt == 4) bf = zj0;
            else if (kt == 5) bf = zj1;
            else if (kt == 6) bf = zj2;
            else if (kt == 7) bf = zj3;
            else if (kt == 8) bf = bmul(zi0, zj0);
            else if (kt == 9) bf = bmul(zi1, zj1);
            else if (kt ==10) bf = bmul(zi2, zj2);
            else              bf = bmul(zi3, zj3);
            const int ko = (kt * 32 + hi * 16) ^ sw;
            bf16x8 a0 = *(const bf16x8*)(w1b + (size_t)el * 384        + ko);
            bf16x8 a1 = *(const bf16x8*)(w1b + (size_t)(32 + el) * 384 + ko);
            acc0 = mfma32(a0, bf, acc0);
            acc1 = mfma32(a1, bf, acc1);
        }

        // ---- hand-off in registers: relu + cvt_pk + permlane32_swap -> 4 B-frags (K=64) ----
        bf16x8 F0, F1, F2, F3;
        epi(acc0, F0, F1);
        epi(acc1, F2, F3);

        // ---- layer 2: out^T[s][e], 8 MFMA over K=64 ----
        f32x16 o0 = bias_init(tb2, hi * 32);          // s 0..31
        f32x16 o1 = bias_init(tb2, hi * 32 + 16);     // s 32..63

#pragma unroll
        for (int k2 = 0; k2 < 4; ++k2) {
            bf16x8 pf = (k2 == 0) ? F0 : (k2 == 1) ? F1 : (k2 == 2) ? F2 : F3;
            const int ko = (k2 * 32 + hi * 16) ^ sw;
            bf16x8 a0 = *(const bf16x8*)(w2b + (size_t)el * 128        + ko);
            bf16x8 a1 = *(const bf16x8*)(w2b + (size_t)(32 + el) * 128 + ko);
            o0 = mfma32(a0, pf, o0);
            o1 = mfma32(a1, pf, o1);
        }

        // ---- store: 8x global_store_dwordx4 ----
        float* orow = out + ((size_t)(m0 + (st * 8 + wave) * 32 + el)) * 64;
#pragma unroll
        for (int p = 0; p < 4; ++p) {
            f32x4 s0v = {o0[4*p], o0[4*p+1], o0[4*p+2], o0[4*p+3]};
            f32x4 s1v = {o1[4*p], o1[4*p+1], o1[4*p+2], o1[4*p+3]};
            *(f32x4*)(orow +      8 * p + 4 * hi) = s0v;
            *(f32x4*)(orow + 32 + 8 * p + 4 * hi) = s1v;
        }
    }
}

extern "C" void kernel_launch(void* const* d_in, const int* in_sizes, int n_in,
                              void* d_out, int out_size, void* d_ws, size_t ws_size,
                              hipStream_t stream) {
    const float* z     = (const float*)d_in[0];
    const int*   pairs = (const int*)  d_in[1];
    const float* W1    = (const float*)d_in[2];
    const float* b1    = (const float*)d_in[3];
    const float* W2    = (const float*)d_in[4];
    const float* b2    = (const float*)d_in[5];
    float* out = (float*)d_out;
    __bf16* zw = (__bf16*)d_ws;   // 2 MB bf16 copy of z

    zcast_kernel<<<Z_ELEMS / (256 * 8), 256, 0, stream>>>(z, zw);

    const int total_rows = 4 * E_TOT;                 // 524288
    dim3 grid(total_rows / ROWS_PER_BLOCK);           // 1024
    PairRelationEncoder_62775241998442_kernel<<<grid, 512, 0, stream>>>(
        zw, pairs, W1, b1, W2, b2, out);
}

// Round 7
// 56.769 us; speedup vs baseline: 1.0202x; 1.0202x over previous
//
#include <hip/hip_runtime.h>
#include <hip/hip_bf16.h>
#include <stdint.h>

// PairRelationEncoder: out[b,e,s] = b2[s] + sum_r W2[s,r]*relu(b1[r] + sum_f W1[r,f]*pair[b,e,f])
// pair = [zi, zj, zi-zj, zi*zj] folded to [zi, zj, zi*zj]: Wzi=W1a+W1c, Wzj=W1b-W1c, Wpr=W1d.
// B=4 N=4096 D=64 E=131072 R=64. Out f32 (4,131072,64).
//
// R7: SPILL FIX. R3-R6 all capped VGPR (128 or 85) below the body's live state (~160-200)
// -> scratch spills inside the loop = unhidden global-latency on the critical path, which
// explains the structure-insensitive ~55-90us wall. Now launch_bounds(256) with NO min-waves
// (512-reg budget, no spill); 256-thr blocks, NSUB=4, grid 1024; LDS 33KB -> 4 blocks/CU
// = 16 waves/CU resident. Structure otherwise = R6 (32x32 MFMA, register hand-off via
// cvt_pk_bf16 + permlane32_swap, LDS weights, bf16-z prologue, XCD swizzle).

typedef __attribute__((ext_vector_type(8)))  __bf16 bf16x8;
typedef __attribute__((ext_vector_type(4)))  float  f32x4;
typedef __attribute__((ext_vector_type(16))) float  f32x16;
typedef __attribute__((ext_vector_type(4)))  uint32_t u32x4;

#define E_TOT 131072
#define N_TOK 4096
#define ROWS_PER_BLOCK 512
#define NSUB 4            // per wave: 4 subtiles x 32 pairs (4 waves -> 512 rows/block)
#define Z_ELEMS (4 * N_TOK * 64)

// ---- prologue: f32 z -> bf16 z in workspace ----
__global__ __launch_bounds__(256) void zcast_kernel(const float* __restrict__ z,
                                                    __bf16* __restrict__ zb)
{
    const int t = blockIdx.x * 256 + threadIdx.x;
    const float4 a = ((const float4*)z)[2 * t];
    const float4 b = ((const float4*)z)[2 * t + 1];
    bf16x8 r;
    r[0] = (__bf16)a.x; r[1] = (__bf16)a.y; r[2] = (__bf16)a.z; r[3] = (__bf16)a.w;
    r[4] = (__bf16)b.x; r[5] = (__bf16)b.y; r[6] = (__bf16)b.z; r[7] = (__bf16)b.w;
    ((bf16x8*)zb)[t] = r;
}

__device__ __forceinline__ f32x16 mfma32(bf16x8 a, bf16x8 b, f32x16 c) {
    return __builtin_amdgcn_mfma_f32_32x32x16_bf16(a, b, c, 0, 0, 0);
}

__device__ __forceinline__ bf16x8 pk8(float4 a, float4 b) {
    bf16x8 r;
    r[0] = (__bf16)a.x; r[1] = (__bf16)a.y; r[2] = (__bf16)a.z; r[3] = (__bf16)a.w;
    r[4] = (__bf16)b.x; r[5] = (__bf16)b.y; r[6] = (__bf16)b.z; r[7] = (__bf16)b.w;
    return r;
}
__device__ __forceinline__ float4 f4add(float4 a, float4 b){ return make_float4(a.x+b.x, a.y+b.y, a.z+b.z, a.w+b.w); }
__device__ __forceinline__ float4 f4sub(float4 a, float4 b){ return make_float4(a.x-b.x, a.y-b.y, a.z-b.z, a.w-b.w); }

__device__ __forceinline__ bf16x8 bmul(bf16x8 a, bf16x8 b) {
    bf16x8 r;
#pragma unroll
    for (int t = 0; t < 8; ++t)
        r[t] = (__bf16)((float)a[t] * (float)b[t]);
    return r;
}

__device__ __forceinline__ uint32_t cvtpk(float lo, float hi) {
    uint32_t w;
    asm("v_cvt_pk_bf16_f32 %0, %1, %2" : "=v"(w) : "v"(lo), "v"(hi));
    return w;
}

// relu + pack one rt's 16 accumulators into two layer-2 B-frags (kappa=2rt, 2rt+1).
__device__ __forceinline__ void epi(const f32x16 acc, bf16x8& fA, bf16x8& fB) {
    float v[16];
#pragma unroll
    for (int t = 0; t < 16; ++t) v[t] = fmaxf(acc[t], 0.f);
    uint32_t w00 = cvtpk(v[0],  v[1]);
    uint32_t w01 = cvtpk(v[2],  v[3]);
    uint32_t w10 = cvtpk(v[4],  v[5]);
    uint32_t w11 = cvtpk(v[6],  v[7]);
    uint32_t w20 = cvtpk(v[8],  v[9]);
    uint32_t w21 = cvtpk(v[10], v[11]);
    uint32_t w30 = cvtpk(v[12], v[13]);
    uint32_t w31 = cvtpk(v[14], v[15]);
    asm("v_permlane32_swap_b32 %0, %1" : "+v"(w00), "+v"(w10));
    asm("v_permlane32_swap_b32 %0, %1" : "+v"(w01), "+v"(w11));
    asm("v_permlane32_swap_b32 %0, %1" : "+v"(w20), "+v"(w30));
    asm("v_permlane32_swap_b32 %0, %1" : "+v"(w21), "+v"(w31));
    u32x4 a = {w00, w01, w10, w11};
    u32x4 b = {w20, w21, w30, w31};
    fA = __builtin_bit_cast(bf16x8, a);
    fB = __builtin_bit_cast(bf16x8, b);
}

__device__ __forceinline__ f32x16 bias_init(const float* tb, int base) {
    f32x16 a;
#pragma unroll
    for (int p = 0; p < 4; ++p) {
        f32x4 c = *(const f32x4*)(tb + base + 4 * p);
        a[4*p+0] = c[0]; a[4*p+1] = c[1]; a[4*p+2] = c[2]; a[4*p+3] = c[3];
    }
    return a;
}

__global__ __launch_bounds__(256) void PairRelationEncoder_62775241998442_kernel(
    const __bf16* __restrict__ zw, const int* __restrict__ pairs,
    const float* __restrict__ W1, const float* __restrict__ b1,
    const float* __restrict__ W2, const float* __restrict__ b2,
    float* __restrict__ out)
{
    const int tid  = threadIdx.x;
    const int wave = tid >> 6;
    const int lane = tid & 63;
    const int el = lane & 31;   // MFMA row (A) / col (B,C)
    const int hi = lane >> 5;   // k-half

    // bijective XCD-chunked swizzle (1024 blocks, 8 XCDs)
    const int bid = (int)(blockIdx.x & 7) * 128 + ((int)blockIdx.x >> 3);
    const int m0 = bid * ROWS_PER_BLOCK;
    const int b  = m0 >> 17;
    const int e0 = m0 & (E_TOT - 1);
    const __bf16* zb = zw + ((size_t)b * N_TOK * 64);

    // hoisted pairs
    int2 ijv[NSUB];
#pragma unroll
    for (int st = 0; st < NSUB; ++st)
        ijv[st] = *(const int2*)(pairs + 2 * (size_t)(e0 + (st * 4 + wave) * 32 + el));

    // LDS: W1f bf16 [r(64)][k(192)] swz + W2 bf16 [s(64)][r(64)] swz + bias tables.
    // 24576 + 8192 + 256 + 256 = 33280 B -> 4 blocks/CU.
    __shared__ __bf16 w1s[64 * 192];
    __shared__ __bf16 w2s[64 * 64];
    __shared__ float  tb1[64];
    __shared__ float  tb2[64];

    // ---- one-time weight staging: 4 parts x 64 threads (part = wave, uniform branch) ----
    {
        const int part = tid >> 6;            // 0:zi 1:zj 2:pr 3:W2
        const int scol = tid & 63;
        const int cswz = (scol & 7) << 4;
        if (part < 3) {
            const float* wr = W1 + (size_t)scol * 256;
            char* dst = (char*)w1s + scol * 384;
#pragma unroll
            for (int c8 = 0; c8 < 8; ++c8) {
                float4 p0, p1;
                if (part == 0) {
                    float4 a0 = *(const float4*)(wr + c8*8);
                    float4 a1 = *(const float4*)(wr + c8*8 + 4);
                    float4 c0 = *(const float4*)(wr + 128 + c8*8);
                    float4 c1 = *(const float4*)(wr + 128 + c8*8 + 4);
                    p0 = f4add(a0, c0); p1 = f4add(a1, c1);
                } else if (part == 1) {
                    float4 a0 = *(const float4*)(wr + 64 + c8*8);
                    float4 a1 = *(const float4*)(wr + 64 + c8*8 + 4);
                    float4 c0 = *(const float4*)(wr + 128 + c8*8);
                    float4 c1 = *(const float4*)(wr + 128 + c8*8 + 4);
                    p0 = f4sub(a0, c0); p1 = f4sub(a1, c1);
                } else {
                    p0 = *(const float4*)(wr + 192 + c8*8);
                    p1 = *(const float4*)(wr + 192 + c8*8 + 4);
                }
                *(bf16x8*)(dst + ((part * 128 + c8 * 16) ^ cswz)) = pk8(p0, p1);
            }
        } else {
            const float* wr = W2 + (size_t)scol * 64;
            char* dst = (char*)w2s + scol * 128;
#pragma unroll
            for (int c8 = 0; c8 < 8; ++c8) {
                float4 p0 = *(const float4*)(wr + c8*8);
                float4 p1 = *(const float4*)(wr + c8*8 + 4);
                *(bf16x8*)(dst + ((c8 * 16) ^ cswz)) = pk8(p0, p1);
            }
        }
        // bias tables: tb[hi*32 + rt*16 + reg] = bias[rt*32 + (reg&3) + 8*((reg>>2)&3) + 4*hi]
        if (tid < 64)
            tb1[tid] = b1[((tid >> 4) & 1) * 32 + (tid & 3) + 8 * ((tid >> 2) & 3) + 4 * (tid >> 5)];
        else if (tid < 128) {
            const int t = tid - 64;
            tb2[t] = b2[((t >> 4) & 1) * 32 + (t & 3) + 8 * ((t >> 2) & 3) + 4 * (t >> 5)];
        }
    }

    __syncthreads();

    const int sw = (el & 7) << 4;
    const char* w1b = (const char*)w1s;
    const char* w2b = (const char*)w2s;

#pragma unroll
    for (int st = 0; st < NSUB; ++st) {
        // ---- gather: 8x 16B loads are the layer-1 B-frags ----
        const __bf16* zri = zb + (size_t)ijv[st].x * 64;
        const __bf16* zrj = zb + (size_t)ijv[st].y * 64;
        bf16x8 zi0 = *(const bf16x8*)(zri +      hi * 8);
        bf16x8 zi1 = *(const bf16x8*)(zri + 16 + hi * 8);
        bf16x8 zi2 = *(const bf16x8*)(zri + 32 + hi * 8);
        bf16x8 zi3 = *(const bf16x8*)(zri + 48 + hi * 8);
        bf16x8 zj0 = *(const bf16x8*)(zrj +      hi * 8);
        bf16x8 zj1 = *(const bf16x8*)(zrj + 16 + hi * 8);
        bf16x8 zj2 = *(const bf16x8*)(zrj + 32 + hi * 8);
        bf16x8 zj3 = *(const bf16x8*)(zrj + 48 + hi * 8);

        // ---- layer 1: h1^T[r][e], 24 MFMA over K=192 ----
        f32x16 acc0 = bias_init(tb1, hi * 32);        // rt=0: r 0..31
        f32x16 acc1 = bias_init(tb1, hi * 32 + 16);   // rt=1: r 32..63

#pragma unroll
        for (int kt = 0; kt < 12; ++kt) {
            bf16x8 bf;
            if      (kt == 0) bf = zi0;
            else if (kt == 1) bf = zi1;
            else if (kt == 2) bf = zi2;
            else if (kt == 3) bf = zi3;
            else if (kt == 4) bf = zj0;
            else if (kt == 5) bf = zj1;
            else if (kt == 6) bf = zj2;
            else if (kt == 7) bf = zj3;
            else if (kt == 8) bf = bmul(zi0, zj0);
            else if (kt == 9) bf = bmul(zi1, zj1);
            else if (kt ==10) bf = bmul(zi2, zj2);
            else              bf = bmul(zi3, zj3);
            const int ko = (kt * 32 + hi * 16) ^ sw;
            bf16x8 a0 = *(const bf16x8*)(w1b + (size_t)el * 384        + ko);
            bf16x8 a1 = *(const bf16x8*)(w1b + (size_t)(32 + el) * 384 + ko);
            acc0 = mfma32(a0, bf, acc0);
            acc1 = mfma32(a1, bf, acc1);
        }

        // ---- hand-off in registers: relu + cvt_pk + permlane32_swap -> 4 B-frags (K=64) ----
        bf16x8 F0, F1, F2, F3;
        epi(acc0, F0, F1);
        epi(acc1, F2, F3);

        // ---- layer 2: out^T[s][e], 8 MFMA over K=64 ----
        f32x16 o0 = bias_init(tb2, hi * 32);          // s 0..31
        f32x16 o1 = bias_init(tb2, hi * 32 + 16);     // s 32..63

#pragma unroll
        for (int k2 = 0; k2 < 4; ++k2) {
            bf16x8 pf = (k2 == 0) ? F0 : (k2 == 1) ? F1 : (k2 == 2) ? F2 : F3;
            const int ko = (k2 * 32 + hi * 16) ^ sw;
            bf16x8 a0 = *(const bf16x8*)(w2b + (size_t)el * 128        + ko);
            bf16x8 a1 = *(const bf16x8*)(w2b + (size_t)(32 + el) * 128 + ko);
            o0 = mfma32(a0, pf, o0);
            o1 = mfma32(a1, pf, o1);
        }

        // ---- store: 8x global_store_dwordx4 ----
        float* orow = out + ((size_t)(m0 + (st * 4 + wave) * 32 + el)) * 64;
#pragma unroll
        for (int p = 0; p < 4; ++p) {
            f32x4 s0v = {o0[4*p], o0[4*p+1], o0[4*p+2], o0[4*p+3]};
            f32x4 s1v = {o1[4*p], o1[4*p+1], o1[4*p+2], o1[4*p+3]};
            *(f32x4*)(orow +      8 * p + 4 * hi) = s0v;
            *(f32x4*)(orow + 32 + 8 * p + 4 * hi) = s1v;
        }
    }
}

extern "C" void kernel_launch(void* const* d_in, const int* in_sizes, int n_in,
                              void* d_out, int out_size, void* d_ws, size_t ws_size,
                              hipStream_t stream) {
    const float* z     = (const float*)d_in[0];
    const int*   pairs = (const int*)  d_in[1];
    const float* W1    = (const float*)d_in[2];
    const float* b1    = (const float*)d_in[3];
    const float* W2    = (const float*)d_in[4];
    const float* b2    = (const float*)d_in[5];
    float* out = (float*)d_out;
    __bf16* zw = (__bf16*)d_ws;   // 2 MB bf16 copy of z

    zcast_kernel<<<Z_ELEMS / (256 * 8), 256, 0, stream>>>(z, zw);

    const int total_rows = 4 * E_TOT;                 // 524288
    dim3 grid(total_rows / ROWS_PER_BLOCK);           // 1024
    PairRelationEncoder_62775241998442_kernel<<<grid, 256, 0, stream>>>(
        zw, pairs, W1, b1, W2, b2, out);
}

// Round 8
// 53.208 us; speedup vs baseline: 1.0885x; 1.0669x over previous
//
#include <hip/hip_runtime.h>
#include <hip/hip_bf16.h>
#include <stdint.h>

// PairRelationEncoder: out[b,e,s] = b2[s] + sum_r W2[s,r]*relu(b1[r] + sum_f W1[r,f]*pair[b,e,f])
// pair = [zi, zj, zi-zj, zi*zj] folded to [zi, zj, zi*zj]: Wzi=W1a+W1c, Wzj=W1b-W1c, Wpr=W1d.
// B=4 N=4096 D=64 E=131072 R=64. Out f32 (4,131072,64).
//
// R8: STRICT REGISTER DIET. Theory: every prior round had unified (VGPR+AGPR) > 128 or a
// cap below live state -> 2 waves/SIMD or in-loop spills; the ~57us wall is latency at
// 8 waves/CU. This round: R5's 16x16 structure (32 AGPR total), z-frags loaded per-h
// (3 live not 6), JIT pr product, linear bias tables, launch_bounds(512,4) = 128-reg cap
// with ~18 regs slack. Target: total ~110 regs, 16 waves/CU.

typedef __attribute__((ext_vector_type(8))) __bf16 bf16x8;
typedef __attribute__((ext_vector_type(4))) __bf16 bf16x4;
typedef __attribute__((ext_vector_type(4))) float  f32x4;

#define E_TOT 131072
#define N_TOK 4096
#define ROWS_PER_BLOCK 512
#define NSUB 4   // per wave: 4 subtiles x 16 pairs (8 waves -> 512 rows/block)
#define Z_ELEMS (4 * N_TOK * 64)

// ---- prologue: f32 z -> bf16 z in workspace ----
__global__ __launch_bounds__(256) void zcast_kernel(const float* __restrict__ z,
                                                    __bf16* __restrict__ zb)
{
    const int t = blockIdx.x * 256 + threadIdx.x;
    const float4 a = ((const float4*)z)[2 * t];
    const float4 b = ((const float4*)z)[2 * t + 1];
    bf16x8 r;
    r[0] = (__bf16)a.x; r[1] = (__bf16)a.y; r[2] = (__bf16)a.z; r[3] = (__bf16)a.w;
    r[4] = (__bf16)b.x; r[5] = (__bf16)b.y; r[6] = (__bf16)b.z; r[7] = (__bf16)b.w;
    ((bf16x8*)zb)[t] = r;
}

__device__ __forceinline__ f32x4 mfma16(bf16x8 a, bf16x8 b, f32x4 c) {
    return __builtin_amdgcn_mfma_f32_16x16x32_bf16(a, b, c, 0, 0, 0);
}

__device__ __forceinline__ bf16x8 pk8(float4 a, float4 b) {
    bf16x8 r;
    r[0] = (__bf16)a.x; r[1] = (__bf16)a.y; r[2] = (__bf16)a.z; r[3] = (__bf16)a.w;
    r[4] = (__bf16)b.x; r[5] = (__bf16)b.y; r[6] = (__bf16)b.z; r[7] = (__bf16)b.w;
    return r;
}
__device__ __forceinline__ float4 f4add(float4 a, float4 b){ return make_float4(a.x+b.x, a.y+b.y, a.z+b.z, a.w+b.w); }
__device__ __forceinline__ float4 f4sub(float4 a, float4 b){ return make_float4(a.x-b.x, a.y-b.y, a.z-b.z, a.w-b.w); }

__device__ __forceinline__ bf16x8 bmul(bf16x8 a, bf16x8 b) {
    bf16x8 r;
#pragma unroll
    for (int t = 0; t < 8; ++t)
        r[t] = (__bf16)((float)a[t] * (float)b[t]);
    return r;
}

__global__ __launch_bounds__(512, 4) void PairRelationEncoder_62775241998442_kernel(
    const __bf16* __restrict__ zw, const int* __restrict__ pairs,
    const float* __restrict__ W1, const float* __restrict__ b1,
    const float* __restrict__ W2, const float* __restrict__ b2,
    float* __restrict__ out)
{
    const int tid  = threadIdx.x;
    const int wave = tid >> 6;
    const int lane = tid & 63;
    const int x = lane & 15;   // e-index within subtile (B-col / C-col)
    const int g = lane >> 4;   // k-group

    // bijective XCD-chunked swizzle (1024 blocks, 8 XCDs)
    const int bid = (int)(blockIdx.x & 7) * 128 + ((int)blockIdx.x >> 3);
    const int m0 = bid * ROWS_PER_BLOCK;
    const int b  = m0 >> 17;
    const int e0 = m0 & (E_TOT - 1);
    const __bf16* zb = zw + ((size_t)b * N_TOK * 64);

    // hoisted pairs (maximal load lead time)
    int2 ijv[NSUB];
#pragma unroll
    for (int st = 0; st < NSUB; ++st)
        ijv[st] = *(const int2*)(pairs + 2 * (size_t)(e0 + (st * 8 + wave) * 16 + x));

    // LDS: W1f bf16 [r(64)][k(192)] swz + W2 bf16 [s(64)][r(64)] swz + per-wave h1^T + bias.
    // 24576 + 8192 + 16384 + 256 + 256 = 49664 B -> 2 blocks/CU.
    __shared__ __bf16 w1s[64 * 192];
    __shared__ __bf16 w2s[64 * 64];
    __shared__ __bf16 h1s[8][1024];
    __shared__ float  b1s[64];
    __shared__ float  b2s[64];
    __bf16* h1w = h1s[wave];

    // ---- one-time weight staging: 8 groups of 64 threads; part x half-of-c8 ----
    {
        const int part = (tid >> 6) & 3;      // 0:zi 1:zj 2:pr 3:W2 (wave-uniform)
        const int scol = tid & 63;
        const int c8b  = (tid >> 8) * 4;      // 0 or 4
        const int cswz = (scol & 7) << 4;
        if (part < 3) {
            const float* wr = W1 + (size_t)scol * 256;
            char* dst = (char*)w1s + scol * 384;
#pragma unroll
            for (int c = 0; c < 4; ++c) {
                const int c8 = c8b + c;
                float4 p0, p1;
                if (part == 0) {
                    float4 a0 = *(const float4*)(wr + c8*8);
                    float4 a1 = *(const float4*)(wr + c8*8 + 4);
                    float4 c0 = *(const float4*)(wr + 128 + c8*8);
                    float4 c1 = *(const float4*)(wr + 128 + c8*8 + 4);
                    p0 = f4add(a0, c0); p1 = f4add(a1, c1);
                } else if (part == 1) {
                    float4 a0 = *(const float4*)(wr + 64 + c8*8);
                    float4 a1 = *(const float4*)(wr + 64 + c8*8 + 4);
                    float4 c0 = *(const float4*)(wr + 128 + c8*8);
                    float4 c1 = *(const float4*)(wr + 128 + c8*8 + 4);
                    p0 = f4sub(a0, c0); p1 = f4sub(a1, c1);
                } else {
                    p0 = *(const float4*)(wr + 192 + c8*8);
                    p1 = *(const float4*)(wr + 192 + c8*8 + 4);
                }
                *(bf16x8*)(dst + ((part * 128 + c8 * 16) ^ cswz)) = pk8(p0, p1);
            }
        } else {
            const float* wr = W2 + (size_t)scol * 64;
            char* dst = (char*)w2s + scol * 128;
#pragma unroll
            for (int c = 0; c < 4; ++c) {
                const int c8 = c8b + c;
                float4 p0 = *(const float4*)(wr + c8*8);
                float4 p1 = *(const float4*)(wr + c8*8 + 4);
                *(bf16x8*)(dst + ((c8 * 16) ^ cswz)) = pk8(p0, p1);
            }
        }
        if (tid < 64)            b1s[tid] = b1[tid];
        else if (tid < 128)      b2s[tid - 64] = b2[tid - 64];
    }

    __syncthreads();

    const int sw = (x & 7) << 4;

#pragma unroll
    for (int st = 0; st < NSUB; ++st) {
        const __bf16* zri = zb + (size_t)ijv[st].x * 64;
        const __bf16* zrj = zb + (size_t)ijv[st].y * 64;

        // ---- layer 1 (transposed): acc[ct][q] = h1[r=ct*16+g*4+q][e=x], init = b1 ----
        f32x4 acc[4];
#pragma unroll
        for (int ct = 0; ct < 4; ++ct)
            acc[ct] = *(const f32x4*)(b1s + ct * 16 + g * 4);

#pragma unroll
        for (int h = 0; h < 2; ++h) {
            // per-h JIT gather: only 3 frags live at a time (12 regs)
            bf16x8 azf = *(const bf16x8*)(zri + h * 32 + g * 8);   // zi half
            bf16x8 bzf = *(const bf16x8*)(zrj + h * 32 + g * 8);   // zj half
            bf16x8 pzf = bmul(azf, bzf);                            // zi*zj half
            const int kb = h * 64 + g * 16;
#pragma unroll
            for (int ct = 0; ct < 4; ++ct) {
                const int colr = ct * 16 + x;
                const int cswz = (colr & 7) << 4;
                const char* wb = (const char*)w1s + colr * 384;
                bf16x8 wzi = *(const bf16x8*)(wb + ((kb      ) ^ cswz));
                bf16x8 wzj = *(const bf16x8*)(wb + ((kb + 128) ^ cswz));
                bf16x8 wpr = *(const bf16x8*)(wb + ((kb + 256) ^ cswz));
                acc[ct] = mfma16(wzi, azf, acc[ct]);
                acc[ct] = mfma16(wzj, bzf, acc[ct]);
                acc[ct] = mfma16(wpr, pzf, acc[ct]);
            }
        }

        // ---- epilogue: relu, pack 4xbf16, one ds_write_b64 per ct (wave-private) ----
#pragma unroll
        for (int ct = 0; ct < 4; ++ct) {
            bf16x4 p;
#pragma unroll
            for (int q = 0; q < 4; ++q)
                p[q] = (__bf16)fmaxf(acc[ct][q], 0.f);
            const int wo = (x * 128 + ct * 32 + g * 8) ^ sw;
            *(bf16x4*)((char*)h1w + wo) = p;
        }

        // ---- layer 2 (transposed): o[ct][q] = out[e=x][s=ct*16+g*4+q], init = b2 ----
        f32x4 o[4];
#pragma unroll
        for (int ct = 0; ct < 4; ++ct)
            o[ct] = *(const f32x4*)(b2s + ct * 16 + g * 4);

#pragma unroll
        for (int kk = 0; kk < 2; ++kk) {
            const int aoff = (x * 128 + kk * 64 + g * 16) ^ sw;
            const bf16x8 h1f = *(const bf16x8*)((const char*)h1w + aoff);
#pragma unroll
            for (int ct = 0; ct < 4; ++ct) {
                const int cols = ct * 16 + x;
                const bf16x8 w2f = *(const bf16x8*)((const char*)w2s + cols * 128
                                                    + ((kk * 64 + g * 16) ^ ((cols & 7) << 4)));
                o[ct] = mfma16(w2f, h1f, o[ct]);
            }
        }

        // ---- store: 4x global_store_dwordx4 ----
        float* orow = out + ((size_t)(m0 + (st * 8 + wave) * 16 + x)) * 64;
#pragma unroll
        for (int ct = 0; ct < 4; ++ct)
            *(f32x4*)(orow + ct * 16 + g * 4) = o[ct];
    }
}

extern "C" void kernel_launch(void* const* d_in, const int* in_sizes, int n_in,
                              void* d_out, int out_size, void* d_ws, size_t ws_size,
                              hipStream_t stream) {
    const float* z     = (const float*)d_in[0];
    const int*   pairs = (const int*)  d_in[1];
    const float* W1    = (const float*)d_in[2];
    const float* b1    = (const float*)d_in[3];
    const float* W2    = (const float*)d_in[4];
    const float* b2    = (const float*)d_in[5];
    float* out = (float*)d_out;
    __bf16* zw = (__bf16*)d_ws;   // 2 MB bf16 copy of z

    zcast_kernel<<<Z_ELEMS / (256 * 8), 256, 0, stream>>>(z, zw);

    const int total_rows = 4 * E_TOT;                 // 524288
    dim3 grid(total_rows / ROWS_PER_BLOCK);           // 1024
    PairRelationEncoder_62775241998442_kernel<<<grid, 512, 0, stream>>>(
        zw, pairs, W1, b1, W2, b2, out);
}